// Round 10
// baseline (350.541 us; speedup 1.0000x reference)
//
#include <hip/hip_runtime.h>
#include <stdint.h>
#include <stddef.h>

// Problem constants (fixed by setup_inputs)
#define N_ROWS 500000
#define DDIM   128
#define K2     256      // 2*D
#define KBOND  32
#define TILE   16
#define NTL    (N_ROWS / TILE)    // 31250, exact (no tail)
#define NBLK   1024               // pass1 blocks = 4 per CU resident
#define MR_BLKS 16                // 1024 / 64
#define P2_BLOCKS 2048

typedef float  f32x4  __attribute__((ext_vector_type(4)));
typedef __bf16 bf16x8 __attribute__((ext_vector_type(8)));
typedef __bf16 bf16x4 __attribute__((ext_vector_type(4)));

// ---- module-scope device scratch ----
__device__ __bf16 g_wbf[DDIM * K2];                    // 64 KiB  W_i_w bf16 [d][k]
__device__ float  g_s[N_ROWS];                         // 2 MiB   s[n] = colsum(bond)
__device__ float  g_partials[NBLK * DDIM];             // 512 KiB
__device__ float  g_p2[MR_BLKS * DDIM];                // 8 KiB
__device__ float  g_msg[DDIM];
__device__ __bf16 g_hn[(size_t)N_ROWS * DDIM];         // 128 MiB h_n bf16

// ---- kernel 1: W_i_w f32 -> bf16 ----
__global__ void k_prep(const float* __restrict__ w) {
  int t = blockIdx.x * blockDim.x + threadIdx.x;
  if (t < DDIM * K2) g_wbf[t] = (__bf16)w[t];
}

// ---- kernel 1b: s[n] = sum_k bond[k][n]  (pure streaming, ~64 MB) ----
__global__ __launch_bounds__(256)
void k_s(const float* __restrict__ bond) {
  int n = blockIdx.x * 256 + threadIdx.x;
  if (n >= N_ROWS) return;
  float a = 0.f, b = 0.f;
  #pragma unroll
  for (int k = 0; k < KBOND; k += 2) {
    a += bond[(size_t)k * N_ROWS + n];
    b += bond[(size_t)(k + 1) * N_ROWS + n];
  }
  g_s[n] = a + b;
}

// ---- kernel 2: fused h_n GEMM + m partial accumulation ----
// R9 structure + DEPTH-2 register pipeline (2x-unrolled, static reg sets
// Ra/Rb -- rule #20) + NBLK=1024 (4 blocks/CU resident, was 3).
// Each phase: prefetch tile t+2*NBLK into the set freed last phase ->
// compute tile t from buf[cur] -> epilogue -> ds_write the OTHER set
// (loaded one full phase ago: auto-vmcnt satisfied, ZERO stall) ->
// lgkm-only raw barrier (h_n stores and fresh loads ride across).
// LDS: R9's measured-zero-conflict bf16 layout: row r (0..15) at r*512 B,
// 16-B slot s at byte (16 s)^((r&15)<<4); x = slots 0-15, he = 16-31.
// MFMA swapped (A=W rows=d, B=data cols=n); A/B share the (g,e)->k map
// k = 32ks+8g+e, so any internal k-permutation cancels (verified R2-R9).
__global__ __launch_bounds__(256, 4)
void k_pass1(const float* __restrict__ x, const float* __restrict__ he,
             const float* __restrict__ bias)
{
  __shared__ __align__(16) unsigned char a_lds[2][TILE * 512];   // 2 x 8 KiB

  const int tid  = threadIdx.x;
  const int w    = tid >> 6;        // wave 0..3: owns d in [32w, 32w+32)
  const int lane = tid & 63;
  const int l15  = lane & 15;
  const int g    = lane >> 4;       // 0..3

  // W fragments for 2 d-groups, all K, in registers: 64 VGPR
  bf16x8 wfrag[2][8];
  #pragma unroll
  for (int dg = 0; dg < 2; ++dg)
    #pragma unroll
    for (int ks = 0; ks < 8; ++ks)
      wfrag[dg][ks] = *(const bf16x8*)(g_wbf +
          (size_t)(32 * w + 16 * dg + l15) * K2 + 32 * ks + 8 * g);

  f32x4 bv0 = *(const f32x4*)(bias + 32 * w + 4 * g);
  f32x4 bv1 = *(const f32x4*)(bias + 32 * w + 16 + 4 * g);

  // staging coords: thread -> (row sr, slot sc); x slot sc, he slot sc+16
  const int sr = tid >> 4;                       // 0..15
  const int sc = tid & 15;                       // 0..15
  const unsigned swz   = (unsigned)(sr << 4);
  const unsigned wo_x  = (unsigned)(sr * 512) + ((16u * sc) ^ swz);
  const unsigned wo_he = (unsigned)(sr * 512) + ((256u + 16u * sc) ^ swz);
  const unsigned rsw   = (unsigned)(l15 << 4);   // read-side swizzle

  f32x4 macc0 = (f32x4)(0.f), macc1 = (f32x4)(0.f);
  int t = blockIdx.x;
  int cur = 0;

  // two static register sets (depth-2 pipeline)
  f32x4 xa0, xb0, ha0, hb0;  float sA;   // set Ra
  f32x4 xa1, xb1, ha1, hb1;  float sB;   // set Rb

  // ---- prologue: Ra <- tile t; Rb <- tile t+NBLK (clamped); Ra -> buf0 ----
  {
    const float* xr = x  + (size_t)(t * TILE + sr) * DDIM + 8 * sc;
    const float* hr = he + (size_t)(t * TILE + sr) * DDIM + 8 * sc;
    xa0 = *(const f32x4*)xr; xb0 = *(const f32x4*)(xr + 4);
    ha0 = *(const f32x4*)hr; hb0 = *(const f32x4*)(hr + 4);
    sA  = g_s[t * TILE + l15];
  }
  {
    const int t1 = t + NBLK;
    const int tl = (t1 < NTL) ? t1 : t;
    const float* xr = x  + (size_t)(tl * TILE + sr) * DDIM + 8 * sc;
    const float* hr = he + (size_t)(tl * TILE + sr) * DDIM + 8 * sc;
    xa1 = *(const f32x4*)xr; xb1 = *(const f32x4*)(xr + 4);
    ha1 = *(const f32x4*)hr; hb1 = *(const f32x4*)(hr + 4);
    sB  = g_s[tl * TILE + l15];
  }
  {
    bf16x8 bx, bh;
    #pragma unroll
    for (int i = 0; i < 4; ++i) {
      bx[i] = (__bf16)xa0[i]; bx[4 + i] = (__bf16)xb0[i];
      bh[i] = (__bf16)ha0[i]; bh[4 + i] = (__bf16)hb0[i];
    }
    *(bf16x8*)(&a_lds[0][wo_x])  = bx;
    *(bf16x8*)(&a_lds[0][wo_he]) = bh;
  }
  __builtin_amdgcn_sched_barrier(0);
  asm volatile("s_waitcnt lgkmcnt(0)");
  __builtin_amdgcn_s_barrier();
  __builtin_amdgcn_sched_barrier(0);

  // PHASE: prefetch t+2*NBLK -> (LXA..LSN); compute tile t with s=SCUR
  // (copied before overwrite); ds_write (WXA..WHB) [tile t+NBLK] -> buf^1.
#define PHASE(LXA,LXB,LHA,LHB,LSN, WXA,WXB,WHA,WHB)                          \
  do {                                                                       \
    const float scur_ = LSN;            /* s for tile t (before overwrite) */\
    const int t2 = t + 2 * NBLK;                                             \
    const int tl = (t2 < NTL) ? t2 : t;                                      \
    const float* xr = x  + (size_t)(tl * TILE + sr) * DDIM + 8 * sc;         \
    const float* hr = he + (size_t)(tl * TILE + sr) * DDIM + 8 * sc;         \
    LXA = *(const f32x4*)xr; LXB = *(const f32x4*)(xr + 4);                  \
    LHA = *(const f32x4*)hr; LHB = *(const f32x4*)(hr + 4);                  \
    LSN = g_s[tl * TILE + l15];                                              \
    __builtin_amdgcn_sched_barrier(0);                                       \
    f32x4 acc0 = (f32x4)(0.f), acc1 = (f32x4)(0.f);                          \
    {                                                                        \
      const unsigned char* base_ = &a_lds[cur][0];                           \
      _Pragma("unroll")                                                      \
      for (int ks = 0; ks < 8; ++ks) {                                       \
        const unsigned o = (unsigned)(64 * ks + 16 * g);                     \
        bf16x8 b = *(const bf16x8*)(base_ + l15 * 512 + (o ^ rsw));          \
        acc0 = __builtin_amdgcn_mfma_f32_16x16x32_bf16(wfrag[0][ks], b, acc0, 0, 0, 0); \
        acc1 = __builtin_amdgcn_mfma_f32_16x16x32_bf16(wfrag[1][ks], b, acc1, 0, 0, 0); \
      }                                                                      \
    }                                                                        \
    {                                                                        \
      const int n_ = t * TILE + l15;                                         \
      f32x4 h0, h1;                                                          \
      _Pragma("unroll")                                                      \
      for (int i = 0; i < 4; ++i) {                                          \
        float a_ = acc0[i] + bv0[i]; h0[i] = a_ > 0.f ? a_ : 0.f;            \
        float b_ = acc1[i] + bv1[i]; h1[i] = b_ > 0.f ? b_ : 0.f;            \
      }                                                                      \
      _Pragma("unroll")                                                      \
      for (int i = 0; i < 4; ++i) { macc0[i] += scur_ * h0[i];               \
                                    macc1[i] += scur_ * h1[i]; }             \
      bf16x4 q0, q1;                                                         \
      _Pragma("unroll")                                                      \
      for (int i = 0; i < 4; ++i) { q0[i] = (__bf16)h0[i];                   \
                                    q1[i] = (__bf16)h1[i]; }                 \
      *(bf16x4*)(g_hn + (size_t)n_ * DDIM + 32 * w + 4 * g)      = q0;       \
      *(bf16x4*)(g_hn + (size_t)n_ * DDIM + 32 * w + 16 + 4 * g) = q1;       \
    }                                                                        \
    __builtin_amdgcn_sched_barrier(0);                                       \
    {                                                                        \
      bf16x8 bx, bh;                                                         \
      _Pragma("unroll")                                                      \
      for (int i = 0; i < 4; ++i) {                                          \
        bx[i] = (__bf16)WXA[i]; bx[4 + i] = (__bf16)WXB[i];                  \
        bh[i] = (__bf16)WHA[i]; bh[4 + i] = (__bf16)WHB[i];                  \
      }                                                                      \
      *(bf16x8*)(&a_lds[cur ^ 1][wo_x])  = bx;                               \
      *(bf16x8*)(&a_lds[cur ^ 1][wo_he]) = bh;                               \
    }                                                                        \
    __builtin_amdgcn_sched_barrier(0);                                       \
    asm volatile("s_waitcnt lgkmcnt(0)");                                    \
    __builtin_amdgcn_s_barrier();                                            \
    __builtin_amdgcn_sched_barrier(0);                                       \
    cur ^= 1;                                                                \
  } while (0)

  for (;;) {
    PHASE(xa0, xb0, ha0, hb0, sA,  xa1, xb1, ha1, hb1);   // compute t (s=sA)
    t += NBLK; if (t >= NTL) break;
    PHASE(xa1, xb1, ha1, hb1, sB,  xa0, xb0, ha0, hb0);   // compute t (s=sB)
    t += NBLK; if (t >= NTL) break;
  }
#undef PHASE

  // ---- block partial for m: sum the 16 l15-lanes (same d quad) ----
  #pragma unroll
  for (int off = 1; off <= 8; off <<= 1) {
    #pragma unroll
    for (int i = 0; i < 4; ++i) {
      macc0[i] += __shfl_xor(macc0[i], off, 64);
      macc1[i] += __shfl_xor(macc1[i], off, 64);
    }
  }
  if (l15 == 0) {
    *(f32x4*)(&g_partials[(size_t)blockIdx.x * DDIM + 32 * w + 4 * g])      = macc0;
    *(f32x4*)(&g_partials[(size_t)blockIdx.x * DDIM + 32 * w + 16 + 4 * g]) = macc1;
  }
}

// ---- kernel 3: parallel partial reduce: NBLK x 128 -> MR_BLKS x 128 ----
__global__ void k_mr() {
  const int d    = threadIdx.x & 127;
  const int half = threadIdx.x >> 7;        // 0/1
  const int r0   = blockIdx.x * 64;
  float acc = 0.f;
  for (int r = r0 + half; r < r0 + 64; r += 2)
    acc += g_partials[(size_t)r * DDIM + d];
  __shared__ float sp[DDIM];
  if (half == 0) sp[d] = acc;
  __syncthreads();
  if (half == 1) g_p2[blockIdx.x * DDIM + d] = sp[d] + acc;
}

// ---- kernel 4: m[d] = sum_c p2[c][d]; msg = W_m m + b_m ----
__global__ void k_msg(const float* __restrict__ wm, const float* __restrict__ bm) {
  __shared__ float ms[DDIM];
  const int d = threadIdx.x;                // 128 threads
  float s = 0.f;
  #pragma unroll
  for (int c = 0; c < MR_BLKS; ++c) s += g_p2[c * DDIM + d];
  ms[d] = s;
  __syncthreads();
  float acc = bm[d];
  #pragma unroll 8
  for (int j = 0; j < DDIM; ++j) acc += ms[j] * wm[(size_t)d * DDIM + j];
  g_msg[d] = acc;
}

// ---- kernel 5: out = relu(h_n + msg) ----
__global__ __launch_bounds__(256)
void k_pass2(float* __restrict__ out)
{
  __shared__ float ms[DDIM];
  if (threadIdx.x < DDIM) ms[threadIdx.x] = g_msg[threadIdx.x];
  __syncthreads();
  const size_t total = (size_t)N_ROWS * DDIM / 8;
  for (size_t c = (size_t)blockIdx.x * blockDim.x + threadIdx.x; c < total;
       c += (size_t)gridDim.x * blockDim.x) {
    const size_t base = c * 8;
    const int col0 = (int)(base & (DDIM - 1));
    bf16x8 hv = *(const bf16x8*)(g_hn + base);
    f32x4 o0, o1;
    #pragma unroll
    for (int i = 0; i < 4; ++i) {
      float a = (float)hv[i]     + ms[col0 + i];
      float b = (float)hv[4 + i] + ms[col0 + 4 + i];
      o0[i] = a > 0.f ? a : 0.f;
      o1[i] = b > 0.f ? b : 0.f;
    }
    *(f32x4*)(out + base)     = o0;
    *(f32x4*)(out + base + 4) = o1;
  }
}

extern "C" void kernel_launch(void* const* d_in, const int* in_sizes, int n_in,
                              void* d_out, int out_size, void* d_ws, size_t ws_size,
                              hipStream_t stream) {
  const float* x    = (const float*)d_in[0];
  const float* he   = (const float*)d_in[1];
  const float* bond = (const float*)d_in[2];
  const float* wi   = (const float*)d_in[3];
  const float* bi   = (const float*)d_in[4];
  const float* wm   = (const float*)d_in[5];
  const float* bm   = (const float*)d_in[6];
  float* out = (float*)d_out;
  (void)d_ws; (void)ws_size;

  k_prep<<<(DDIM * K2 + 255) / 256, 256, 0, stream>>>(wi);
  k_s<<<(N_ROWS + 255) / 256, 256, 0, stream>>>(bond);
  k_pass1<<<NBLK, 256, 0, stream>>>(x, he, bi);
  k_mr<<<MR_BLKS, 256, 0, stream>>>();
  k_msg<<<1, 128, 0, stream>>>(wm, bm);
  k_pass2<<<P2_BLOCKS, 256, 0, stream>>>(out);
}